// Round 13
// baseline (157.891 us; speedup 1.0000x reference)
//
#include <hip/hip_runtime.h>
#include <hip/hip_bf16.h>

typedef unsigned short u16;
typedef __attribute__((ext_vector_type(8))) short bf16x8;
typedef __attribute__((ext_vector_type(4))) float f32x4;

typedef __attribute__((address_space(1))) const void cgvoid;
typedef __attribute__((address_space(3))) void lvoid;

static __device__ __forceinline__ u16 f2bf(float x) {
    __hip_bfloat16 h = __float2bfloat16(x);
    return __builtin_bit_cast(u16, h);
}
static __device__ __forceinline__ float bf2f(u16 x) {
    return __builtin_bit_cast(float, ((unsigned)x) << 16);
}

static __device__ __forceinline__ void gload_lds16(const u16* g, u16* l) {
    __builtin_amdgcn_global_load_lds((cgvoid*)g, (lvoid*)l, 16, 0, 0);
}

// ---------------------------------------------------------------------------
// prep: blocks [0,2048) = LayerNorm1 rows; blocks [2048,6144) = grid-stride
// f32->bf16 convert of all four weight matrices.
// ---------------------------------------------------------------------------
__global__ __launch_bounds__(256) void prep(
    const float* __restrict__ hidden, const float* __restrict__ g1,
    const float* __restrict__ b1, u16* __restrict__ ln_out,
    const float* __restrict__ qkv_w, const float* __restrict__ dense_w,
    const float* __restrict__ fc1_w, const float* __restrict__ fc2_w,
    u16* __restrict__ qkv_wb, u16* __restrict__ dense_wb,
    u16* __restrict__ fc1_wb, u16* __restrict__ fc2_wb)
{
    const int t = threadIdx.x;
    if (blockIdx.x < 2048) {
        const int row = blockIdx.x;
        const float4 v = ((const float4*)(hidden + (size_t)row * 1024))[t];
        float s  = v.x + v.y + v.z + v.w;
        float sq = v.x*v.x + v.y*v.y + v.z*v.z + v.w*v.w;
#pragma unroll
        for (int d = 1; d < 64; d <<= 1) {
            s  += __shfl_xor(s, d, 64);
            sq += __shfl_xor(sq, d, 64);
        }
        __shared__ float ss[4], ssq[4];
        const int wave = t >> 6, lane = t & 63;
        if (lane == 0) { ss[wave] = s; ssq[wave] = sq; }
        __syncthreads();
        s  = ss[0] + ss[1] + ss[2] + ss[3];
        sq = ssq[0] + ssq[1] + ssq[2] + ssq[3];
        const float mu = s * (1.f / 1024.f);
        const float rinv = rsqrtf(sq * (1.f / 1024.f) - mu * mu + 1e-5f);
        const float4 gv = ((const float4*)g1)[t];
        const float4 bv = ((const float4*)b1)[t];
        ushort4 pk;
        pk.x = f2bf((v.x - mu) * rinv * gv.x + bv.x);
        pk.y = f2bf((v.y - mu) * rinv * gv.y + bv.y);
        pk.z = f2bf((v.z - mu) * rinv * gv.z + bv.z);
        pk.w = f2bf((v.w - mu) * rinv * gv.w + bv.w);
        ((ushort4*)(ln_out + (size_t)row * 1024))[t] = pk;
        return;
    }
    constexpr int C0 = 786432;            // qkv   3072*1024/4
    constexpr int C1 = C0 + 262144;       // dense 1024*1024/4
    constexpr int C2 = C1 + 1048576;      // fc1   4096*1024/4
    constexpr int C3 = C2 + 1048576;      // fc2   1024*4096/4
    int i = (blockIdx.x - 2048) * 256 + t;
    const int stride = (gridDim.x - 2048) * 256;
    for (; i < C3; i += stride) {
        const float* src; u16* dst; int j;
        if (i < C0)      { src = qkv_w;   dst = qkv_wb;   j = i; }
        else if (i < C1) { src = dense_w; dst = dense_wb; j = i - C0; }
        else if (i < C2) { src = fc1_w;   dst = fc1_wb;   j = i - C1; }
        else             { src = fc2_w;   dst = fc2_wb;   j = i - C2; }
        const float4 v = ((const float4*)src)[j];
        ushort4 pk;
        pk.x = f2bf(v.x); pk.y = f2bf(v.y); pk.z = f2bf(v.z); pk.w = f2bf(v.w);
        ((ushort4*)dst)[j] = pk;
    }
}

// ---------------------------------------------------------------------------
// C[M][N] = A[M][K] @ W[N][K]^T (+ bias + epilogue)
// BM in {64,128}, BN in {64,128}, BK=64, 4 waves, single-buffered.
// EPI: 0 = bf16 out (+bias), 2 = bf16 out + bias + bloom-gelu,
//      3 = QKV epilogue: packs Q/K/V into fragment buffers,
//      4 = raw bf16 partial (NO bias) to p0 (z==0) / pext[z-1],
//      5 = bf16 out = acc + bias + resi (f32 residual read)
// ---------------------------------------------------------------------------
template<int EPI, int BM, int BN>
__global__ __launch_bounds__(256, (BN == 128) ? 3 : 4) void gemm_bt(
    const u16* __restrict__ A, const u16* __restrict__ Bw,
    const float* __restrict__ bias, const float* __restrict__ resi,
    void* __restrict__ Cout,
    u16* __restrict__ p0, u16* __restrict__ pext,
    u16* __restrict__ qPo, u16* __restrict__ kPo, u16* __restrict__ vPo,
    int M, int N, int K, int Kspan)
{
    constexpr int WC = BN / 64;          // waves along N
    constexpr int WR = 4 / WC;           // waves along M
    constexpr int MI = BM / (WR * 16);
    constexpr int NI = 4;
    __shared__ __align__(16) u16 As[BM * 64];
    __shared__ __align__(16) u16 Bs[BN * 64];
    const int t = threadIdx.x;
    const int lane = t & 63;
    const int wave = t >> 6;
    const int wr = wave / WC, wc = wave % WC;
    const int g = lane >> 4, r16 = lane & 15;

    // XCD m-chunked swizzle (requires gridDim.x*gridDim.y % 8 == 0)
    const int nxy = gridDim.x * gridDim.y;
    const int bid0 = blockIdx.x + gridDim.x * blockIdx.y;
    const int v = (bid0 & 7) * (nxy >> 3) + (bid0 >> 3);
    const int tile_m = (v / gridDim.y) * BM;
    const int tile_n = (v % gridDim.y) * BN;
    const int kb = blockIdx.z * Kspan;

    f32x4 acc[MI][NI] = {};

    for (int k0 = kb; k0 < kb + Kspan; k0 += 64) {
        __syncthreads();
#pragma unroll
        for (int i = 0; i < BM / 32; ++i) {
            const int off = (t + i * 256) * 8;
            gload_lds16(A + (size_t)(tile_m + (off >> 6)) * K + k0 + (off & 63), As + off);
        }
#pragma unroll
        for (int i = 0; i < BN / 32; ++i) {
            const int off = (t + i * 256) * 8;
            gload_lds16(Bw + (size_t)(tile_n + (off >> 6)) * K + k0 + (off & 63), Bs + off);
        }
        __syncthreads();

        bf16x8 af[MI][2], bfr[NI][2];
#pragma unroll
        for (int mi = 0; mi < MI; ++mi)
#pragma unroll
            for (int ks = 0; ks < 2; ++ks)
                af[mi][ks] = *(const bf16x8*)(As + (wr*(MI*16) + mi*16 + r16)*64 + ks*32 + g*8);
#pragma unroll
        for (int ni = 0; ni < NI; ++ni)
#pragma unroll
            for (int ks = 0; ks < 2; ++ks)
                bfr[ni][ks] = *(const bf16x8*)(Bs + (wc*64 + ni*16 + r16)*64 + ks*32 + g*8);
#pragma unroll
        for (int mi = 0; mi < MI; ++mi)
#pragma unroll
            for (int ni = 0; ni < NI; ++ni) {
                acc[mi][ni] = __builtin_amdgcn_mfma_f32_16x16x32_bf16(af[mi][0], bfr[ni][0], acc[mi][ni], 0, 0, 0);
                acc[mi][ni] = __builtin_amdgcn_mfma_f32_16x16x32_bf16(af[mi][1], bfr[ni][1], acc[mi][ni], 0, 0, 0);
            }
    }

    u16* dst = nullptr;
    if constexpr (EPI == 4)
        dst = (blockIdx.z == 0) ? p0 : pext + (size_t)(blockIdx.z - 1) * ((size_t)M * N);

#pragma unroll
    for (int mi = 0; mi < MI; ++mi) {
#pragma unroll
        for (int ni = 0; ni < NI; ++ni) {
            const int col = tile_n + wc*64 + ni*16 + r16;
            const int row0 = tile_m + wr*(MI*16) + mi*16 + g*4;
            float vv[4];
#pragma unroll
            for (int r = 0; r < 4; ++r) {
                if constexpr (EPI == 4) vv[r] = acc[mi][ni][r];
                else                    vv[r] = acc[mi][ni][r] + bias[col];
            }
            if constexpr (EPI != 3) {
#pragma unroll
                for (int r = 0; r < 4; ++r) {
                    const int row = row0 + r;
                    if constexpr (EPI == 4) {
                        dst[(size_t)row * N + col] = f2bf(vv[r]);
                    } else if constexpr (EPI == 0) {
                        ((u16*)Cout)[(size_t)row * N + col] = f2bf(vv[r]);
                    } else if constexpr (EPI == 5) {
                        ((u16*)Cout)[(size_t)row * N + col] =
                            f2bf(vv[r] + resi[(size_t)row * N + col]);
                    } else {
                        const float c = 0.79788456f * vv[r] * (1.0f + 0.044715f * vv[r] * vv[r]);
                        ((u16*)Cout)[(size_t)row * N + col] = f2bf(vv[r] / (1.0f + __expf(-2.0f * c)));
                    }
                }
            } else {
                // QKV epilogue: pack Q/K/V fragments only (no row-major store)
                const int h = col / 192;
                const int fm = col % 192;
                if ((fm >> 6) == 0) {                 // Q feature
                    const int f = fm;
                    const int ks = f >> 5, gg = (f >> 3) & 3, e = f & 7;
#pragma unroll
                    for (int r = 0; r < 4; ++r) {
                        const int tkn = row0 + r;
                        const int qt = tkn >> 4, rr = tkn & 15;
                        qPo[((size_t)(h*128 + qt)*2 + ks)*512 + (gg*16 + rr)*8 + e] = f2bf(vv[r]);
                    }
                } else if ((fm >> 6) == 1) {          // K feature
                    const int f = fm - 64;
                    const int ks = f >> 5, gg = (f >> 3) & 3, e = f & 7;
#pragma unroll
                    for (int r = 0; r < 4; ++r) {
                        const int tkn = row0 + r;
                        const int kt = tkn >> 6, w = tkn & 63;
                        const int kn = ((w >> 5) << 1) | ((w >> 2) & 1);
                        const int rp = ((w >> 3) & 3) * 4 + (w & 3);
                        kPo[((size_t)(h*32 + kt))*4096 + (kn*2 + ks)*512 + (gg*16 + rp)*8 + e] = f2bf(vv[r]);
                    }
                } else {                              // V feature
                    const int f = fm - 128;
                    const int nd = f >> 4, rv = f & 15;
                    const int kt = row0 >> 6, w = row0 & 63;
                    const int ks = w >> 5, gg = (w >> 3) & 3, e0 = w & 7;
                    ushort4 pk4;
                    pk4.x = f2bf(vv[0]); pk4.y = f2bf(vv[1]);
                    pk4.z = f2bf(vv[2]); pk4.w = f2bf(vv[3]);
                    *(ushort4*)(vPo + ((size_t)(h*32 + kt))*4096 + (nd*2 + ks)*512 + (gg*16 + rv)*8 + e0) = pk4;
                }
            }
        }
    }
}

// ---------------------------------------------------------------------------
// LN2: ln_out = LayerNorm(attn_o) where attn_o is bf16. One block per row.
// ---------------------------------------------------------------------------
__global__ __launch_bounds__(256) void ln2_bf16(
    const u16* __restrict__ x, const float* __restrict__ g2,
    const float* __restrict__ b2, u16* __restrict__ ln_out)
{
    const int row = blockIdx.x;
    const int t = threadIdx.x;
    const ushort4 xa = ((const ushort4*)(x + (size_t)row * 1024))[t];
    float4 v;
    v.x = bf2f(xa.x); v.y = bf2f(xa.y); v.z = bf2f(xa.z); v.w = bf2f(xa.w);

    float s  = v.x + v.y + v.z + v.w;
    float sq = v.x*v.x + v.y*v.y + v.z*v.z + v.w*v.w;
#pragma unroll
    for (int d = 1; d < 64; d <<= 1) {
        s  += __shfl_xor(s, d, 64);
        sq += __shfl_xor(sq, d, 64);
    }
    __shared__ float ss[4], ssq[4];
    const int wave = t >> 6, lane = t & 63;
    if (lane == 0) { ss[wave] = s; ssq[wave] = sq; }
    __syncthreads();
    s  = ss[0] + ss[1] + ss[2] + ss[3];
    sq = ssq[0] + ssq[1] + ssq[2] + ssq[3];
    const float mu = s * (1.f / 1024.f);
    const float rinv = rsqrtf(sq * (1.f / 1024.f) - mu * mu + 1e-5f);
    const float4 gv = ((const float4*)g2)[t];
    const float4 b2v = ((const float4*)b2)[t];
    ushort4 pk;
    pk.x = f2bf((v.x - mu) * rinv * gv.x + b2v.x);
    pk.y = f2bf((v.y - mu) * rinv * gv.y + b2v.y);
    pk.z = f2bf((v.z - mu) * rinv * gv.z + b2v.z);
    pk.w = f2bf((v.w - mu) * rinv * gv.w + b2v.w);
    ((ushort4*)(ln_out + (size_t)row * 1024))[t] = pk;
}

// ---------------------------------------------------------------------------
// out = sum of NP bf16 partials + bias + res(bf16)   (f32 out)
// ---------------------------------------------------------------------------
template<int NP>
__global__ __launch_bounds__(256) void reduce_bias_res(
    const u16* __restrict__ p0, const u16* __restrict__ pext,
    const float* __restrict__ bias, const u16* __restrict__ res,
    float* __restrict__ out, int n4, int n4row)
{
    int i = blockIdx.x * blockDim.x + threadIdx.x;
    const int stride = gridDim.x * blockDim.x;
    for (; i < n4; i += stride) {
        const ushort4 a0 = ((const ushort4*)p0)[i];
        float ax = bf2f(a0.x), ay = bf2f(a0.y), az = bf2f(a0.z), aw = bf2f(a0.w);
#pragma unroll
        for (int j = 0; j < NP - 1; ++j) {
            const ushort4 b = ((const ushort4*)pext)[(size_t)j * n4 + i];
            ax += bf2f(b.x); ay += bf2f(b.y); az += bf2f(b.z); aw += bf2f(b.w);
        }
        const float4 bv = ((const float4*)bias)[i & (n4row - 1)];
        const ushort4 rv = ((const ushort4*)res)[i];
        float4 o;
        o.x = ax + bv.x + bf2f(rv.x);
        o.y = ay + bv.y + bf2f(rv.y);
        o.z = az + bv.z + bf2f(rv.z);
        o.w = aw + bv.w + bf2f(rv.w);
        ((float4*)out)[i] = o;
    }
}

// ---------------------------------------------------------------------------
// Swapped-operand flash attention, 4-way K-split, fragment-packed Q/K/V.
// 2048 blocks, heavy q-tiles dispatched first. setprio around MFMA clusters.
// ---------------------------------------------------------------------------
__global__ __launch_bounds__(256, 4) void attn_swapped(
    const u16* __restrict__ qP, const u16* __restrict__ kP,
    const u16* __restrict__ vP, const float* __restrict__ alibi,
    u16* __restrict__ ctx)
{
    const int bid = blockIdx.x;
    const int h = bid & 15;
    const int qt = 127 - (bid >> 4);        // heavy q-tiles dispatch first
    const int qw0 = qt * 16;
    const int t = threadIdx.x;
    const int lane = t & 63, wave = t >> 6;
    const int g = lane >> 4, r16 = lane & 15;
    const int qrow = qw0 + r16;

    __shared__ float Ms[4][16], Ls[4][16];
    __shared__ float Os[4][4][16][17];      // [wave][nd][d16][q] padded

    bf16x8 qf[2];
    qf[0] = *(const bf16x8*)(qP + ((size_t)(h*128 + qt)*2 + 0)*512 + lane*8);
    qf[1] = *(const bf16x8*)(qP + ((size_t)(h*128 + qt)*2 + 1)*512 + lane*8);

    f32x4 o_acc[4] = {};
    float m_r = -3.0e38f, l_r = 0.f;

    const u16* kPh = kP + (size_t)h * 32 * 4096;
    const u16* vPh = vP + (size_t)h * 32 * 4096;
    const float* abase = alibi + (size_t)h * 2048;

    const int nkt = (qw0 >> 6) + 1;
    for (int kt = wave; kt < nkt; kt += 4) {
        const int kt0 = kt * 64;
        const u16* kT = kPh + (size_t)kt * 4096;
        const u16* vT = vPh + (size_t)kt * 4096;

        bf16x8 kf[4][2], vf[4][2];
#pragma unroll
        for (int kn = 0; kn < 4; ++kn) {
            kf[kn][0] = *(const bf16x8*)(kT + (kn*2 + 0)*512 + lane*8);
            kf[kn][1] = *(const bf16x8*)(kT + (kn*2 + 1)*512 + lane*8);
        }
        float4 al[4];
#pragma unroll
        for (int kn = 0; kn < 4; ++kn)
            al[kn] = *(const float4*)(abase + kt0 + 32*(kn>>1) + 8*g + 4*(kn&1));
#pragma unroll
        for (int nd = 0; nd < 4; ++nd) {
            vf[nd][0] = *(const bf16x8*)(vT + (nd*2 + 0)*512 + lane*8);
            vf[nd][1] = *(const bf16x8*)(vT + (nd*2 + 1)*512 + lane*8);
        }

        f32x4 sc[4] = {};
        __builtin_amdgcn_s_setprio(1);
#pragma unroll
        for (int kn = 0; kn < 4; ++kn) {
            sc[kn] = __builtin_amdgcn_mfma_f32_16x16x32_bf16(kf[kn][0], qf[0], sc[kn], 0, 0, 0);
            sc[kn] = __builtin_amdgcn_mfma_f32_16x16x32_bf16(kf[kn][1], qf[1], sc[kn], 0, 0, 0);
        }
        __builtin_amdgcn_s_setprio(0);

        float s[4][4];
        float rmax = -3.0e38f;
#pragma unroll
        for (int kn = 0; kn < 4; ++kn) {
            const int kb = kt0 + 32*(kn>>1) + 8*g + 4*(kn&1);
            const float alv[4] = {al[kn].x, al[kn].y, al[kn].z, al[kn].w};
#pragma unroll
            for (int r = 0; r < 4; ++r) {
                float v = sc[kn][r] * 0.125f + alv[r];
                v = (kb + r <= qrow) ? v : -1.0e30f;
                s[kn][r] = v;
                rmax = fmaxf(rmax, v);
            }
        }
        rmax = fmaxf(rmax, __shfl_xor(rmax, 16, 64));
        rmax = fmaxf(rmax, __shfl_xor(rmax, 32, 64));

        const float mnew = fmaxf(m_r, rmax);
        const float scale = __expf(m_r - mnew);
        m_r = mnew;

        float psum = 0.f;
        u16 ph[4][4];
#pragma unroll
        for (int kn = 0; kn < 4; ++kn)
#pragma unroll
            for (int r = 0; r < 4; ++r) {
                const float p = __expf(s[kn][r] - mnew);
                psum += p;
                ph[kn][r] = f2bf(p);
            }
        psum += __shfl_xor(psum, 16, 64);
        psum += __shfl_xor(psum, 32, 64);
        l_r = l_r * scale + psum;

#pragma unroll
        for (int nd = 0; nd < 4; ++nd)
#pragma unroll
            for (int r = 0; r < 4; ++r)
                o_acc[nd][r] *= scale;

        bf16x8 pf[2];
#pragma unroll
        for (int ks = 0; ks < 2; ++ks) {
            union { bf16x8 v; u16 e[8]; } u;
#pragma unroll
            for (int r = 0; r < 4; ++r) { u.e[r] = ph[2*ks][r]; u.e[4+r] = ph[2*ks+1][r]; }
            pf[ks] = u.v;
        }
        __builtin_amdgcn_s_setprio(1);
#pragma unroll
        for (int nd = 0; nd < 4; ++nd) {
            o_acc[nd] = __builtin_amdgcn_mfma_f32_16x16x32_bf16(vf[nd][0], pf[0], o_acc[nd], 0, 0, 0);
            o_acc[nd] = __builtin_amdgcn_mfma_f32_16x16x32_bf16(vf[nd][1], pf[1], o_acc[nd], 0, 0, 0);
        }
        __builtin_amdgcn_s_setprio(0);
    }

    // -------- merge 4 per-wave partials --------
#pragma unroll
    for (int nd = 0; nd < 4; ++nd)
#pragma unroll
        for (int r = 0; r < 4; ++r)
            Os[wave][nd][g*4 + r][r16] = o_acc[nd][r];
    if (g == 0) { Ms[wave][r16] = m_r; Ls[wave][r16] = l_r; }
    __syncthreads();

    if (wave == 0) {
        const float m0 = Ms[0][r16], m1 = Ms[1][r16], m2 = Ms[2][r16], m3 = Ms[3][r16];
        const float ms = fmaxf(fmaxf(m0, m1), fmaxf(m2, m3));
        const float f0 = __expf(m0 - ms), f1 = __expf(m1 - ms);
        const float f2 = __expf(m2 - ms), f3 = __expf(m3 - ms);
        const float l = f0*Ls[0][r16] + f1*Ls[1][r16] + f2*Ls[2][r16] + f3*Ls[3][r16];
        const float inv = 1.0f / l;
#pragma unroll
        for (int nd = 0; nd < 4; ++nd) {
            float v[4];
#pragma unroll
            for (int r = 0; r < 4; ++r) {
                const int d = g*4 + r;
                v[r] = (f0*Os[0][nd][d][r16] + f1*Os[1][nd][d][r16] +
                        f2*Os[2][nd][d][r16] + f3*Os[3][nd][d][r16]) * inv;
            }
            ushort4 pk;
            pk.x = f2bf(v[0]); pk.y = f2bf(v[1]); pk.z = f2bf(v[2]); pk.w = f2bf(v[3]);
            *(ushort4*)(ctx + (size_t)qrow * 1024 + h*64 + nd*16 + g*4) = pk;
        }
    }
}

// ---------------------------------------------------------------------------
extern "C" void kernel_launch(void* const* d_in, const int* in_sizes, int n_in,
                              void* d_out, int out_size, void* d_ws, size_t ws_size,
                              hipStream_t stream)
{
    (void)in_sizes; (void)n_in; (void)out_size; (void)ws_size;
    const float* hidden  = (const float*)d_in[0];
    const float* alibi   = (const float*)d_in[2];
    const float* ln1_g   = (const float*)d_in[3];
    const float* ln1_b   = (const float*)d_in[4];
    const float* qkv_w   = (const float*)d_in[5];
    const float* qkv_b   = (const float*)d_in[6];
    const float* dense_w = (const float*)d_in[7];
    const float* dense_b = (const float*)d_in[8];
    const float* ln2_g   = (const float*)d_in[9];
    const float* ln2_b   = (const float*)d_in[10];
    const float* fc1_w   = (const float*)d_in[11];
    const float* fc1_b   = (const float*)d_in[12];
    const float* fc2_w   = (const float*)d_in[13];
    const float* fc2_b   = (const float*)d_in[14];
    float* out = (float*)d_out;

    char* p = (char*)d_ws;
    u16* ln_buf   = (u16*)p;  p += (size_t)2048 * 1024 * 2;   // [0,4MB)
    u16* qkv_wb   = (u16*)p;  p += (size_t)3072 * 1024 * 2;   // [4,10)
    u16* qP       = (u16*)p;  p += (size_t)2048 * 3072 * 2;   // [10,22) qP(4MB)+slack; hbuf aliases
    u16* ctx      = (u16*)p;  p += (size_t)2048 * 1024 * 2;   // [22,26)
    u16* dense_wb = (u16*)p;  p += (size_t)1024 * 1024 * 2;   // [26,28)
    u16* kvbuf    = (u16*)p;  p += (size_t)2048 * 1024 * 4;   // [28,36) kP+vP, then attn_o
    u16* fc1_wb   = (u16*)p;  p += (size_t)4096 * 1024 * 2;   // [36,44)
    u16* fc2_wb   = (u16*)p;  p += (size_t)1024 * 4096 * 2;   // [44,52)
    u16* pext     = (u16*)p;  p += (size_t)3 * 2048 * 1024 * 2; // [52,64) bf16 split-K slices 1..3
    u16* part0    = (u16*)p;  p += (size_t)2048 * 1024 * 2;   // [64,68) bf16 split-K slice 0
    u16* hbuf = qP;                // FC1 out (16MB) aliases qP+ctx region (dead)
    u16* kP = kvbuf;               // 4MB
    u16* vP = kP + (size_t)16 * 32 * 4096;    // 4MB
    u16* attn_o = kvbuf;           // bf16 attn_o (4MB) reuses kP region (dead after attn)

    // LN1 + all weight converts, one dispatch
    prep<<<6144, 256, 0, stream>>>(hidden, ln1_g, ln1_b, ln_buf,
                                   qkv_w, dense_w, fc1_w, fc2_w,
                                   qkv_wb, dense_wb, fc1_wb, fc2_wb);
    // QKV: 128x64 tiles, 768 blocks, packs Q/K/V fragments only
    gemm_bt<3,128,64><<<dim3(16, 48), 256, 0, stream>>>(ln_buf, qkv_wb, qkv_b, nullptr, nullptr,
                                                        nullptr, nullptr, qP, kP, vP,
                                                        2048, 3072, 1024, 1024);
    // attention: 2048 blocks, heavy-first, packed Q/K/V
    attn_swapped<<<2048, 256, 0, stream>>>(qP, kP, vP, alibi, ctx);
    // dense: single-pass 64x64 tiles, 512 blocks (4/CU); epilogue fuses
    // bias + residual(hidden f32) -> bf16 attn_o (overwrites dead kP region)
    gemm_bt<5,64,64><<<dim3(32, 16), 256, 0, stream>>>(ctx, dense_wb, dense_b, hidden, attn_o,
                                                       nullptr, nullptr, nullptr, nullptr, nullptr,
                                                       2048, 1024, 1024, 1024);
    // LN2 over bf16 attn_o
    ln2_bf16<<<2048, 256, 0, stream>>>(attn_o, ln2_g, ln2_b, ln_buf);
    // FC1 + gelu: 128x128 tiles, 512 blocks
    gemm_bt<2,128,128><<<dim3(16, 32), 256, 0, stream>>>(ln_buf, fc1_wb, fc1_b, nullptr, hbuf,
                                                         nullptr, nullptr, nullptr, nullptr, nullptr,
                                                         2048, 4096, 1024, 1024);
    // FC2: 128x128, split-K=4, 512 blocks, bf16 partials
    gemm_bt<4,128,128><<<dim3(16, 8, 4), 256, 0, stream>>>(hbuf, fc2_wb, nullptr, nullptr, nullptr,
                                                           part0, pext, nullptr, nullptr, nullptr,
                                                           2048, 1024, 4096, 1024);
    reduce_bias_res<4><<<2048, 256, 0, stream>>>(part0, pext, fc2_b, attn_o, out,
                                                 2048*1024/4, 256);
}

// Round 14
// 154.735 us; speedup vs baseline: 1.0204x; 1.0204x over previous
//
#include <hip/hip_runtime.h>
#include <hip/hip_bf16.h>

typedef unsigned short u16;
typedef __attribute__((ext_vector_type(8))) short bf16x8;
typedef __attribute__((ext_vector_type(4))) float f32x4;

typedef __attribute__((address_space(1))) const void cgvoid;
typedef __attribute__((address_space(3))) void lvoid;

static __device__ __forceinline__ u16 f2bf(float x) {
    __hip_bfloat16 h = __float2bfloat16(x);
    return __builtin_bit_cast(u16, h);
}
static __device__ __forceinline__ float bf2f(u16 x) {
    return __builtin_bit_cast(float, ((unsigned)x) << 16);
}

static __device__ __forceinline__ void gload_lds16(const u16* g, u16* l) {
    __builtin_amdgcn_global_load_lds((cgvoid*)g, (lvoid*)l, 16, 0, 0);
}

// ---------------------------------------------------------------------------
// prep: blocks [0,2048) = LayerNorm1 rows; blocks [2048,6144) = grid-stride
// f32->bf16 convert of all four weight matrices.
// ---------------------------------------------------------------------------
__global__ __launch_bounds__(256) void prep(
    const float* __restrict__ hidden, const float* __restrict__ g1,
    const float* __restrict__ b1, u16* __restrict__ ln_out,
    const float* __restrict__ qkv_w, const float* __restrict__ dense_w,
    const float* __restrict__ fc1_w, const float* __restrict__ fc2_w,
    u16* __restrict__ qkv_wb, u16* __restrict__ dense_wb,
    u16* __restrict__ fc1_wb, u16* __restrict__ fc2_wb)
{
    const int t = threadIdx.x;
    if (blockIdx.x < 2048) {
        const int row = blockIdx.x;
        const float4 v = ((const float4*)(hidden + (size_t)row * 1024))[t];
        float s  = v.x + v.y + v.z + v.w;
        float sq = v.x*v.x + v.y*v.y + v.z*v.z + v.w*v.w;
#pragma unroll
        for (int d = 1; d < 64; d <<= 1) {
            s  += __shfl_xor(s, d, 64);
            sq += __shfl_xor(sq, d, 64);
        }
        __shared__ float ss[4], ssq[4];
        const int wave = t >> 6, lane = t & 63;
        if (lane == 0) { ss[wave] = s; ssq[wave] = sq; }
        __syncthreads();
        s  = ss[0] + ss[1] + ss[2] + ss[3];
        sq = ssq[0] + ssq[1] + ssq[2] + ssq[3];
        const float mu = s * (1.f / 1024.f);
        const float rinv = rsqrtf(sq * (1.f / 1024.f) - mu * mu + 1e-5f);
        const float4 gv = ((const float4*)g1)[t];
        const float4 bv = ((const float4*)b1)[t];
        ushort4 pk;
        pk.x = f2bf((v.x - mu) * rinv * gv.x + bv.x);
        pk.y = f2bf((v.y - mu) * rinv * gv.y + bv.y);
        pk.z = f2bf((v.z - mu) * rinv * gv.z + bv.z);
        pk.w = f2bf((v.w - mu) * rinv * gv.w + bv.w);
        ((ushort4*)(ln_out + (size_t)row * 1024))[t] = pk;
        return;
    }
    constexpr int C0 = 786432;            // qkv   3072*1024/4
    constexpr int C1 = C0 + 262144;       // dense 1024*1024/4
    constexpr int C2 = C1 + 1048576;      // fc1   4096*1024/4
    constexpr int C3 = C2 + 1048576;      // fc2   1024*4096/4
    int i = (blockIdx.x - 2048) * 256 + t;
    const int stride = (gridDim.x - 2048) * 256;
    for (; i < C3; i += stride) {
        const float* src; u16* dst; int j;
        if (i < C0)      { src = qkv_w;   dst = qkv_wb;   j = i; }
        else if (i < C1) { src = dense_w; dst = dense_wb; j = i - C0; }
        else if (i < C2) { src = fc1_w;   dst = fc1_wb;   j = i - C1; }
        else             { src = fc2_w;   dst = fc2_wb;   j = i - C2; }
        const float4 v = ((const float4*)src)[j];
        ushort4 pk;
        pk.x = f2bf(v.x); pk.y = f2bf(v.y); pk.z = f2bf(v.z); pk.w = f2bf(v.w);
        ((ushort4*)dst)[j] = pk;
    }
}

// ---------------------------------------------------------------------------
// C[M][N] = A[M][K] @ W[N][K]^T (+ bias + epilogue)
// BM=128, BN in {64,128}, BK=64, 4 waves, single-buffered (round-6 loop).
// EPI: 0 = bf16 out (+bias), 2 = bf16 out + bias + bloom-gelu,
//      3 = QKV epilogue: packs Q/K/V into fragment buffers,
//      4 = raw bf16 partial (NO bias) to p0 (z==0) / pext[z-1]
// ---------------------------------------------------------------------------
template<int EPI, int BM, int BN>
__global__ __launch_bounds__(256, (BN == 128) ? 3 : 4) void gemm_bt(
    const u16* __restrict__ A, const u16* __restrict__ Bw,
    const float* __restrict__ bias, void* __restrict__ Cout,
    u16* __restrict__ p0, u16* __restrict__ pext,
    u16* __restrict__ qPo, u16* __restrict__ kPo, u16* __restrict__ vPo,
    int M, int N, int K, int Kspan)
{
    constexpr int WC = BN / 64;          // waves along N
    constexpr int WR = 4 / WC;           // waves along M
    constexpr int MI = BM / (WR * 16);
    constexpr int NI = 4;
    __shared__ __align__(16) u16 As[BM * 64];
    __shared__ __align__(16) u16 Bs[BN * 64];
    const int t = threadIdx.x;
    const int lane = t & 63;
    const int wave = t >> 6;
    const int wr = wave / WC, wc = wave % WC;
    const int g = lane >> 4, r16 = lane & 15;

    // XCD m-chunked swizzle (requires gridDim.x*gridDim.y % 8 == 0)
    const int nxy = gridDim.x * gridDim.y;
    const int bid0 = blockIdx.x + gridDim.x * blockIdx.y;
    const int v = (bid0 & 7) * (nxy >> 3) + (bid0 >> 3);
    const int tile_m = (v / gridDim.y) * BM;
    const int tile_n = (v % gridDim.y) * BN;
    const int kb = blockIdx.z * Kspan;

    f32x4 acc[MI][NI] = {};

    for (int k0 = kb; k0 < kb + Kspan; k0 += 64) {
        __syncthreads();
#pragma unroll
        for (int i = 0; i < BM / 32; ++i) {
            const int off = (t + i * 256) * 8;
            gload_lds16(A + (size_t)(tile_m + (off >> 6)) * K + k0 + (off & 63), As + off);
        }
#pragma unroll
        for (int i = 0; i < BN / 32; ++i) {
            const int off = (t + i * 256) * 8;
            gload_lds16(Bw + (size_t)(tile_n + (off >> 6)) * K + k0 + (off & 63), Bs + off);
        }
        __syncthreads();

        bf16x8 af[MI][2], bfr[NI][2];
#pragma unroll
        for (int mi = 0; mi < MI; ++mi)
#pragma unroll
            for (int ks = 0; ks < 2; ++ks)
                af[mi][ks] = *(const bf16x8*)(As + (wr*(MI*16) + mi*16 + r16)*64 + ks*32 + g*8);
#pragma unroll
        for (int ni = 0; ni < NI; ++ni)
#pragma unroll
            for (int ks = 0; ks < 2; ++ks)
                bfr[ni][ks] = *(const bf16x8*)(Bs + (wc*64 + ni*16 + r16)*64 + ks*32 + g*8);
#pragma unroll
        for (int mi = 0; mi < MI; ++mi)
#pragma unroll
            for (int ni = 0; ni < NI; ++ni) {
                acc[mi][ni] = __builtin_amdgcn_mfma_f32_16x16x32_bf16(af[mi][0], bfr[ni][0], acc[mi][ni], 0, 0, 0);
                acc[mi][ni] = __builtin_amdgcn_mfma_f32_16x16x32_bf16(af[mi][1], bfr[ni][1], acc[mi][ni], 0, 0, 0);
            }
    }

    u16* dst = nullptr;
    if constexpr (EPI == 4)
        dst = (blockIdx.z == 0) ? p0 : pext + (size_t)(blockIdx.z - 1) * ((size_t)M * N);

#pragma unroll
    for (int mi = 0; mi < MI; ++mi) {
#pragma unroll
        for (int ni = 0; ni < NI; ++ni) {
            const int col = tile_n + wc*64 + ni*16 + r16;
            const int row0 = tile_m + wr*(MI*16) + mi*16 + g*4;
            float vv[4];
#pragma unroll
            for (int r = 0; r < 4; ++r) {
                if constexpr (EPI == 4) vv[r] = acc[mi][ni][r];
                else                    vv[r] = acc[mi][ni][r] + bias[col];
            }
            if constexpr (EPI != 3) {
#pragma unroll
                for (int r = 0; r < 4; ++r) {
                    const int row = row0 + r;
                    if constexpr (EPI == 4) {
                        dst[(size_t)row * N + col] = f2bf(vv[r]);
                    } else if constexpr (EPI == 0) {
                        ((u16*)Cout)[(size_t)row * N + col] = f2bf(vv[r]);
                    } else {
                        const float c = 0.79788456f * vv[r] * (1.0f + 0.044715f * vv[r] * vv[r]);
                        ((u16*)Cout)[(size_t)row * N + col] = f2bf(vv[r] / (1.0f + __expf(-2.0f * c)));
                    }
                }
            } else {
                // QKV epilogue: pack Q/K/V fragments only (no row-major store)
                const int h = col / 192;
                const int fm = col % 192;
                if ((fm >> 6) == 0) {                 // Q feature
                    const int f = fm;
                    const int ks = f >> 5, gg = (f >> 3) & 3, e = f & 7;
#pragma unroll
                    for (int r = 0; r < 4; ++r) {
                        const int tkn = row0 + r;
                        const int qt = tkn >> 4, rr = tkn & 15;
                        qPo[((size_t)(h*128 + qt)*2 + ks)*512 + (gg*16 + rr)*8 + e] = f2bf(vv[r]);
                    }
                } else if ((fm >> 6) == 1) {          // K feature
                    const int f = fm - 64;
                    const int ks = f >> 5, gg = (f >> 3) & 3, e = f & 7;
#pragma unroll
                    for (int r = 0; r < 4; ++r) {
                        const int tkn = row0 + r;
                        const int kt = tkn >> 6, w = tkn & 63;
                        const int kn = ((w >> 5) << 1) | ((w >> 2) & 1);
                        const int rp = ((w >> 3) & 3) * 4 + (w & 3);
                        kPo[((size_t)(h*32 + kt))*4096 + (kn*2 + ks)*512 + (gg*16 + rp)*8 + e] = f2bf(vv[r]);
                    }
                } else {                              // V feature
                    const int f = fm - 128;
                    const int nd = f >> 4, rv = f & 15;
                    const int kt = row0 >> 6, w = row0 & 63;
                    const int ks = w >> 5, gg = (w >> 3) & 3, e0 = w & 7;
                    ushort4 pk4;
                    pk4.x = f2bf(vv[0]); pk4.y = f2bf(vv[1]);
                    pk4.z = f2bf(vv[2]); pk4.w = f2bf(vv[3]);
                    *(ushort4*)(vPo + ((size_t)(h*32 + kt))*4096 + (nd*2 + ks)*512 + (gg*16 + rv)*8 + e0) = pk4;
                }
            }
        }
    }
}

// ---------------------------------------------------------------------------
// dense epilogue: v = p0 + p1 (bf16 partials) + bias + res(f32);
// attn_o (bf16) = v; ln_out = LayerNorm(v). One block per row.
// ---------------------------------------------------------------------------
__global__ __launch_bounds__(256) void reduce2_ln(
    const u16* __restrict__ p0, const u16* __restrict__ p1,
    const float* __restrict__ bias, const float* __restrict__ res,
    u16* __restrict__ attn_o, const float* __restrict__ g2,
    const float* __restrict__ b2, u16* __restrict__ ln_out)
{
    const int row = blockIdx.x;
    const int t = threadIdx.x;
    const size_t i = (size_t)row * 256 + t;
    const ushort4 a0 = ((const ushort4*)p0)[i];
    const ushort4 a1 = ((const ushort4*)p1)[i];
    const float4 bv = ((const float4*)bias)[t];
    const float4 rv = ((const float4*)res)[i];
    float4 v;
    v.x = bf2f(a0.x) + bf2f(a1.x) + bv.x + rv.x;
    v.y = bf2f(a0.y) + bf2f(a1.y) + bv.y + rv.y;
    v.z = bf2f(a0.z) + bf2f(a1.z) + bv.z + rv.z;
    v.w = bf2f(a0.w) + bf2f(a1.w) + bv.w + rv.w;
    ushort4 ao;
    ao.x = f2bf(v.x); ao.y = f2bf(v.y); ao.z = f2bf(v.z); ao.w = f2bf(v.w);
    ((ushort4*)attn_o)[i] = ao;

    float s  = v.x + v.y + v.z + v.w;
    float sq = v.x*v.x + v.y*v.y + v.z*v.z + v.w*v.w;
#pragma unroll
    for (int d = 1; d < 64; d <<= 1) {
        s  += __shfl_xor(s, d, 64);
        sq += __shfl_xor(sq, d, 64);
    }
    __shared__ float ss[4], ssq[4];
    const int wave = t >> 6, lane = t & 63;
    if (lane == 0) { ss[wave] = s; ssq[wave] = sq; }
    __syncthreads();
    s  = ss[0] + ss[1] + ss[2] + ss[3];
    sq = ssq[0] + ssq[1] + ssq[2] + ssq[3];
    const float mu = s * (1.f / 1024.f);
    const float rinv = rsqrtf(sq * (1.f / 1024.f) - mu * mu + 1e-5f);
    const float4 gv = ((const float4*)g2)[t];
    const float4 b2v = ((const float4*)b2)[t];
    ushort4 pk;
    pk.x = f2bf((v.x - mu) * rinv * gv.x + b2v.x);
    pk.y = f2bf((v.y - mu) * rinv * gv.y + b2v.y);
    pk.z = f2bf((v.z - mu) * rinv * gv.z + b2v.z);
    pk.w = f2bf((v.w - mu) * rinv * gv.w + b2v.w);
    ((ushort4*)(ln_out + (size_t)row * 1024))[t] = pk;
}

// ---------------------------------------------------------------------------
// out = sum of NP bf16 partials + bias + res(bf16)   (f32 out)
// ---------------------------------------------------------------------------
template<int NP>
__global__ __launch_bounds__(256) void reduce_bias_res(
    const u16* __restrict__ p0, const u16* __restrict__ pext,
    const float* __restrict__ bias, const u16* __restrict__ res,
    float* __restrict__ out, int n4, int n4row)
{
    int i = blockIdx.x * blockDim.x + threadIdx.x;
    const int stride = gridDim.x * blockDim.x;
    for (; i < n4; i += stride) {
        const ushort4 a0 = ((const ushort4*)p0)[i];
        float ax = bf2f(a0.x), ay = bf2f(a0.y), az = bf2f(a0.z), aw = bf2f(a0.w);
#pragma unroll
        for (int j = 0; j < NP - 1; ++j) {
            const ushort4 b = ((const ushort4*)pext)[(size_t)j * n4 + i];
            ax += bf2f(b.x); ay += bf2f(b.y); az += bf2f(b.z); aw += bf2f(b.w);
        }
        const float4 bv = ((const float4*)bias)[i & (n4row - 1)];
        const ushort4 rv = ((const ushort4*)res)[i];
        float4 o;
        o.x = ax + bv.x + bf2f(rv.x);
        o.y = ay + bv.y + bf2f(rv.y);
        o.z = az + bv.z + bf2f(rv.z);
        o.w = aw + bv.w + bf2f(rv.w);
        ((float4*)out)[i] = o;
    }
}

// ---------------------------------------------------------------------------
// Swapped-operand flash attention, 4-way K-split, fragment-packed Q/K/V.
// 2048 blocks, heavy q-tiles dispatched first (r10 schedule). No setprio.
// ---------------------------------------------------------------------------
__global__ __launch_bounds__(256, 4) void attn_swapped(
    const u16* __restrict__ qP, const u16* __restrict__ kP,
    const u16* __restrict__ vP, const float* __restrict__ alibi,
    u16* __restrict__ ctx)
{
    const int bid = blockIdx.x;
    const int h = bid & 15;
    const int qt = 127 - (bid >> 4);        // heavy q-tiles dispatch first
    const int qw0 = qt * 16;
    const int t = threadIdx.x;
    const int lane = t & 63, wave = t >> 6;
    const int g = lane >> 4, r16 = lane & 15;
    const int qrow = qw0 + r16;

    __shared__ float Ms[4][16], Ls[4][16];
    __shared__ float Os[4][4][16][17];      // [wave][nd][d16][q] padded

    bf16x8 qf[2];
    qf[0] = *(const bf16x8*)(qP + ((size_t)(h*128 + qt)*2 + 0)*512 + lane*8);
    qf[1] = *(const bf16x8*)(qP + ((size_t)(h*128 + qt)*2 + 1)*512 + lane*8);

    f32x4 o_acc[4] = {};
    float m_r = -3.0e38f, l_r = 0.f;

    const u16* kPh = kP + (size_t)h * 32 * 4096;
    const u16* vPh = vP + (size_t)h * 32 * 4096;
    const float* abase = alibi + (size_t)h * 2048;

    const int nkt = (qw0 >> 6) + 1;
    for (int kt = wave; kt < nkt; kt += 4) {
        const int kt0 = kt * 64;
        const u16* kT = kPh + (size_t)kt * 4096;
        const u16* vT = vPh + (size_t)kt * 4096;

        bf16x8 kf[4][2], vf[4][2];
#pragma unroll
        for (int kn = 0; kn < 4; ++kn) {
            kf[kn][0] = *(const bf16x8*)(kT + (kn*2 + 0)*512 + lane*8);
            kf[kn][1] = *(const bf16x8*)(kT + (kn*2 + 1)*512 + lane*8);
        }
        float4 al[4];
#pragma unroll
        for (int kn = 0; kn < 4; ++kn)
            al[kn] = *(const float4*)(abase + kt0 + 32*(kn>>1) + 8*g + 4*(kn&1));
#pragma unroll
        for (int nd = 0; nd < 4; ++nd) {
            vf[nd][0] = *(const bf16x8*)(vT + (nd*2 + 0)*512 + lane*8);
            vf[nd][1] = *(const bf16x8*)(vT + (nd*2 + 1)*512 + lane*8);
        }

        f32x4 sc[4] = {};
#pragma unroll
        for (int kn = 0; kn < 4; ++kn) {
            sc[kn] = __builtin_amdgcn_mfma_f32_16x16x32_bf16(kf[kn][0], qf[0], sc[kn], 0, 0, 0);
            sc[kn] = __builtin_amdgcn_mfma_f32_16x16x32_bf16(kf[kn][1], qf[1], sc[kn], 0, 0, 0);
        }

        float s[4][4];
        float rmax = -3.0e38f;
#pragma unroll
        for (int kn = 0; kn < 4; ++kn) {
            const int kb = kt0 + 32*(kn>>1) + 8*g + 4*(kn&1);
            const float alv[4] = {al[kn].x, al[kn].y, al[kn].z, al[kn].w};
#pragma unroll
            for (int r = 0; r < 4; ++r) {
                float v = sc[kn][r] * 0.125f + alv[r];
                v = (kb + r <= qrow) ? v : -1.0e30f;
                s[kn][r] = v;
                rmax = fmaxf(rmax, v);
            }
        }
        rmax = fmaxf(rmax, __shfl_xor(rmax, 16, 64));
        rmax = fmaxf(rmax, __shfl_xor(rmax, 32, 64));

        const float mnew = fmaxf(m_r, rmax);
        const float scale = __expf(m_r - mnew);
        m_r = mnew;

        float psum = 0.f;
        u16 ph[4][4];
#pragma unroll
        for (int kn = 0; kn < 4; ++kn)
#pragma unroll
            for (int r = 0; r < 4; ++r) {
                const float p = __expf(s[kn][r] - mnew);
                psum += p;
                ph[kn][r] = f2bf(p);
            }
        psum += __shfl_xor(psum, 16, 64);
        psum += __shfl_xor(psum, 32, 64);
        l_r = l_r * scale + psum;

#pragma unroll
        for (int nd = 0; nd < 4; ++nd)
#pragma unroll
            for (int r = 0; r < 4; ++r)
                o_acc[nd][r] *= scale;

        bf16x8 pf[2];
#pragma unroll
        for (int ks = 0; ks < 2; ++ks) {
            union { bf16x8 v; u16 e[8]; } u;
#pragma unroll
            for (int r = 0; r < 4; ++r) { u.e[r] = ph[2*ks][r]; u.e[4+r] = ph[2*ks+1][r]; }
            pf[ks] = u.v;
        }
#pragma unroll
        for (int nd = 0; nd < 4; ++nd) {
            o_acc[nd] = __builtin_amdgcn_mfma_f32_16x16x32_bf16(vf[nd][0], pf[0], o_acc[nd], 0, 0, 0);
            o_acc[nd] = __builtin_amdgcn_mfma_f32_16x16x32_bf16(vf[nd][1], pf[1], o_acc[nd], 0, 0, 0);
        }
    }

    // -------- merge 4 per-wave partials --------
#pragma unroll
    for (int nd = 0; nd < 4; ++nd)
#pragma unroll
        for (int r = 0; r < 4; ++r)
            Os[wave][nd][g*4 + r][r16] = o_acc[nd][r];
    if (g == 0) { Ms[wave][r16] = m_r; Ls[wave][r16] = l_r; }
    __syncthreads();

    if (wave == 0) {
        const float m0 = Ms[0][r16], m1 = Ms[1][r16], m2 = Ms[2][r16], m3 = Ms[3][r16];
        const float ms = fmaxf(fmaxf(m0, m1), fmaxf(m2, m3));
        const float f0 = __expf(m0 - ms), f1 = __expf(m1 - ms);
        const float f2 = __expf(m2 - ms), f3 = __expf(m3 - ms);
        const float l = f0*Ls[0][r16] + f1*Ls[1][r16] + f2*Ls[2][r16] + f3*Ls[3][r16];
        const float inv = 1.0f / l;
#pragma unroll
        for (int nd = 0; nd < 4; ++nd) {
            float v[4];
#pragma unroll
            for (int r = 0; r < 4; ++r) {
                const int d = g*4 + r;
                v[r] = (f0*Os[0][nd][d][r16] + f1*Os[1][nd][d][r16] +
                        f2*Os[2][nd][d][r16] + f3*Os[3][nd][d][r16]) * inv;
            }
            ushort4 pk;
            pk.x = f2bf(v[0]); pk.y = f2bf(v[1]); pk.z = f2bf(v[2]); pk.w = f2bf(v[3]);
            *(ushort4*)(ctx + (size_t)qrow * 1024 + h*64 + nd*16 + g*4) = pk;
        }
    }
}

// ---------------------------------------------------------------------------
extern "C" void kernel_launch(void* const* d_in, const int* in_sizes, int n_in,
                              void* d_out, int out_size, void* d_ws, size_t ws_size,
                              hipStream_t stream)
{
    (void)in_sizes; (void)n_in; (void)out_size; (void)ws_size;
    const float* hidden  = (const float*)d_in[0];
    const float* alibi   = (const float*)d_in[2];
    const float* ln1_g   = (const float*)d_in[3];
    const float* ln1_b   = (const float*)d_in[4];
    const float* qkv_w   = (const float*)d_in[5];
    const float* qkv_b   = (const float*)d_in[6];
    const float* dense_w = (const float*)d_in[7];
    const float* dense_b = (const float*)d_in[8];
    const float* ln2_g   = (const float*)d_in[9];
    const float* ln2_b   = (const float*)d_in[10];
    const float* fc1_w   = (const float*)d_in[11];
    const float* fc1_b   = (const float*)d_in[12];
    const float* fc2_w   = (const float*)d_in[13];
    const float* fc2_b   = (const float*)d_in[14];
    float* out = (float*)d_out;

    char* p = (char*)d_ws;
    u16* ln_buf   = (u16*)p;  p += (size_t)2048 * 1024 * 2;   // [0,4MB)
    u16* qkv_wb   = (u16*)p;  p += (size_t)3072 * 1024 * 2;   // [4,10)
    u16* qP       = (u16*)p;  p += (size_t)2048 * 3072 * 2;   // [10,22) qP(4MB)+slack; hbuf aliases
    u16* ctx      = (u16*)p;  p += (size_t)2048 * 1024 * 2;   // [22,26)
    u16* dense_wb = (u16*)p;  p += (size_t)1024 * 1024 * 2;   // [26,28)
    u16* kvbuf    = (u16*)p;  p += (size_t)2048 * 1024 * 4;   // [28,36) kP+vP; attn_o reuses kP
    u16* fc1_wb   = (u16*)p;  p += (size_t)4096 * 1024 * 2;   // [36,44)
    u16* fc2_wb   = (u16*)p;  p += (size_t)1024 * 4096 * 2;   // [44,52)
    u16* pext     = (u16*)p;  p += (size_t)3 * 2048 * 1024 * 2; // [52,64) bf16 split-K slices 1..3
    u16* part0    = (u16*)p;  p += (size_t)2048 * 1024 * 2;   // [64,68) bf16 split-K slice 0
    u16* hbuf = qP;                // FC1 out (16MB) aliases qP+ctx region (dead)
    u16* kP = kvbuf;               // 4MB
    u16* vP = kP + (size_t)16 * 32 * 4096;    // 4MB
    u16* attn_o = kP;              // bf16 attn_o (4MB) reuses kP region (dead after attn)

    // LN1 + all weight converts, one dispatch
    prep<<<6144, 256, 0, stream>>>(hidden, ln1_g, ln1_b, ln_buf,
                                   qkv_w, dense_w, fc1_w, fc2_w,
                                   qkv_wb, dense_wb, fc1_wb, fc2_wb);
    // QKV: 128x64 tiles, 768 blocks, packs Q/K/V fragments only
    gemm_bt<3,128,64><<<dim3(16, 48), 256, 0, stream>>>(ln_buf, qkv_wb, qkv_b, nullptr,
                                                        nullptr, nullptr, qP, kP, vP,
                                                        2048, 3072, 1024, 1024);
    // attention: 2048 blocks, heavy-first, packed Q/K/V
    attn_swapped<<<2048, 256, 0, stream>>>(qP, kP, vP, alibi, ctx);
    // dense: 128x64, split-K=2, 512 blocks, bf16 partials
    gemm_bt<4,128,64><<<dim3(16, 16, 2), 256, 0, stream>>>(ctx, dense_wb, nullptr, nullptr,
                                                           part0, pext, nullptr, nullptr, nullptr,
                                                           2048, 1024, 1024, 512);
    // fused: attn_o(bf16) = partials+bias+residual; ln_buf = LN2
    reduce2_ln<<<2048, 256, 0, stream>>>(part0, pext, dense_b, hidden, attn_o,
                                         ln2_g, ln2_b, ln_buf);
    // FC1 + gelu: 128x128 tiles, 512 blocks
    gemm_bt<2,128,128><<<dim3(16, 32), 256, 0, stream>>>(ln_buf, fc1_wb, fc1_b, hbuf,
                                                         nullptr, nullptr, nullptr, nullptr, nullptr,
                                                         2048, 4096, 1024, 1024);
    // FC2: 128x128, split-K=4, 512 blocks, bf16 partials
    gemm_bt<4,128,128><<<dim3(16, 8, 4), 256, 0, stream>>>(hbuf, fc2_wb, nullptr, nullptr,
                                                           part0, pext, nullptr, nullptr, nullptr,
                                                           2048, 1024, 4096, 1024);
    reduce_bias_res<4><<<2048, 256, 0, stream>>>(part0, pext, fc2_b, attn_o, out,
                                                 2048*1024/4, 256);
}